// Round 2
// baseline (628.777 us; speedup 1.0000x reference)
//
#include <hip/hip_runtime.h>

#define NN 4096
#define IN_F 256
#define OUT_F 64
#define K_CH 4
#define ALPHA 0.2f

typedef __bf16 bf16;
typedef __attribute__((ext_vector_type(8))) __bf16 bf16x8;
typedef __attribute__((ext_vector_type(4))) float f32x4;

// ---------------- k0: Wh = h@W (fp32) ; Wh1 = Wh@a[:64] ; Wh2 = Wh@a[64:]
// grid 1024 x 256: one wave per row i, lane = output feature f.
__global__ __launch_bounds__(256) void k0_wh(const float* __restrict__ h,
                                             const float* __restrict__ W,
                                             const float* __restrict__ a,
                                             float* __restrict__ Wh,
                                             float* __restrict__ Wh1,
                                             float* __restrict__ Wh2) {
    int tid = threadIdx.x;
    int wave = tid >> 6, lane = tid & 63;
    int i = blockIdx.x * 4 + wave;
    const float* hrow = h + (size_t)i * IN_F;
    float acc = 0.f;
    #pragma unroll 8
    for (int c = 0; c < IN_F; ++c)
        acc += hrow[c] * W[c * OUT_F + lane];
    Wh[(size_t)i * OUT_F + lane] = acc;
    float v1 = acc * a[lane];
    float v2 = acc * a[OUT_F + lane];
    #pragma unroll
    for (int o = 32; o > 0; o >>= 1) {
        v1 += __shfl_xor(v1, o, 64);
        v2 += __shfl_xor(v2, o, 64);
    }
    if (lane == 0) { Wh1[i] = v1; Wh2[i] = v2; }
}

// ---------------- k0T: WhT[f][j] = (bf16)Wh[j][f]   (for MFMA B-fragments)
__global__ __launch_bounds__(256) void k0_transpose(const float* __restrict__ Wh,
                                                    bf16* __restrict__ WhT) {
    __shared__ float lds[OUT_F * 65];
    int tid = threadIdx.x;
    int i0 = blockIdx.x * 64;
    int f = tid & 63;
    int r0 = tid >> 6;
    #pragma unroll
    for (int s = 0; s < 16; ++s) {
        int r = r0 * 16 + s;
        lds[f * 65 + r] = Wh[(size_t)(i0 + r) * OUT_F + f];
    }
    __syncthreads();
    int f2 = tid >> 2;
    int c0 = (tid & 3) * 16;
    #pragma unroll
    for (int s = 0; s < 16; ++s) {
        int c = c0 + s;
        WhT[(size_t)f2 * NN + i0 + c] = (bf16)lds[f2 * 65 + c];
    }
}

// ---------------- k1: s_col[k][j] = sum_i (edge>0 ? exp(leaky(Wh1[i]+Wh2[j])*edge) : 0)
// No max-subtraction: e <= ~15, exp cannot overflow fp32.
// grid (64 ichunk, 2 jhalf, 4 k) x 256. Thread owns 8 consecutive j (2x16B loads).
__global__ __launch_bounds__(256) void k1_colsum(const float* __restrict__ edge,
                                                 const float* __restrict__ Wh1,
                                                 const float* __restrict__ Wh2,
                                                 float* __restrict__ s_col) {
    int tid = threadIdx.x;
    int kch = blockIdx.z;
    int j0 = blockIdx.y * 2048 + tid * 8;
    int ibase = blockIdx.x * 64;
    float w2[8];
    {
        f32x4 t0 = *(const f32x4*)&Wh2[j0];
        f32x4 t1 = *(const f32x4*)&Wh2[j0 + 4];
        #pragma unroll
        for (int c = 0; c < 4; ++c) { w2[c] = t0[c]; w2[c + 4] = t1[c]; }
    }
    float s[8] = {0.f, 0.f, 0.f, 0.f, 0.f, 0.f, 0.f, 0.f};
    const float* base = edge + ((size_t)kch * NN + ibase) * NN + j0;
    #pragma unroll 4
    for (int ii = 0; ii < 64; ++ii) {
        float wh1 = Wh1[ibase + ii];
        f32x4 e0 = *(const f32x4*)(base + (size_t)ii * NN);
        f32x4 e1 = *(const f32x4*)(base + (size_t)ii * NN + 4);
        #pragma unroll
        for (int c = 0; c < 8; ++c) {
            float ef = c < 4 ? e0[c] : e1[c - 4];
            float xv = wh1 + w2[c];
            float lk = xv > 0.f ? xv : ALPHA * xv;
            s[c] += ef > 0.f ? __expf(lk * ef) : 0.f;
        }
    }
    #pragma unroll
    for (int c = 0; c < 8; ++c)
        atomicAdd(&s_col[kch * NN + j0 + c], s[c]);
}

// ---------------- k2: fused att computation + att write + hp = att @ Wh (MFMA)
// grid (64 itile, 4 k, 4 jpart) x 256 (4 waves). Wave owns a 16-row stripe.
// Thread layout matches mfma_f32_16x16x32_bf16 A-fragment:
//   A[m = lane&15][k = (lane>>4)*8 + c]  -> row i = itile*64+wave*16+(lane&15),
//   8 consecutive j per lane -> 32B edge load / att store.
// B-fragment: B[k][n]: n = lane&15, k = (lane>>4)*8 + c -> 16B load from WhT (bf16).
__global__ __launch_bounds__(256) void k2_fused(const float* __restrict__ edge,
                                                const float* __restrict__ Wh1,
                                                const float* __restrict__ Wh2,
                                                const float* __restrict__ s_col,
                                                const bf16* __restrict__ WhT,
                                                float* __restrict__ att_out,
                                                float* __restrict__ hp_part) {
    __shared__ float lds_inv[1024];
    __shared__ float lds_w2[1024];
    int tid = threadIdx.x;
    int itile = blockIdx.x;
    int kch = blockIdx.y;
    int jp = blockIdx.z;
    int jbase0 = jp * 1024;
    {   // per-block: 1/s and Wh2 for this j-slab into LDS
        int t4 = tid * 4;
        f32x4 sv = *(const f32x4*)&s_col[kch * NN + jbase0 + t4];
        f32x4 wv = *(const f32x4*)&Wh2[jbase0 + t4];
        f32x4 iv;
        #pragma unroll
        for (int c = 0; c < 4; ++c) iv[c] = sv[c] > 0.f ? 1.f / sv[c] : 0.f;
        *(f32x4*)&lds_inv[t4] = iv;
        *(f32x4*)&lds_w2[t4] = wv;
    }
    __syncthreads();
    int wave = tid >> 6, lane = tid & 63;
    int n16 = lane & 15, quad = lane >> 4;
    int i_row = itile * 64 + wave * 16 + n16;
    float wh1 = Wh1[i_row];
    const size_t erow = ((size_t)kch * NN + i_row) * (size_t)NN;
    f32x4 acc[4] = {};
    #pragma unroll 2
    for (int jt = 0; jt < 16; ++jt) {
        #pragma unroll
        for (int ks = 0; ks < 2; ++ks) {
            int jl = jt * 64 + ks * 32 + quad * 8;   // local j in [0,1024)
            int jg = jbase0 + jl;
            f32x4 e0 = *(const f32x4*)(edge + erow + jg);
            f32x4 e1 = *(const f32x4*)(edge + erow + jg + 4);
            f32x4 iv0 = *(const f32x4*)&lds_inv[jl];
            f32x4 iv1 = *(const f32x4*)&lds_inv[jl + 4];
            f32x4 wv0 = *(const f32x4*)&lds_w2[jl];
            f32x4 wv1 = *(const f32x4*)&lds_w2[jl + 4];
            bf16x8 afrag;
            f32x4 av0, av1;
            #pragma unroll
            for (int c = 0; c < 8; ++c) {
                float ef = c < 4 ? e0[c] : e1[c - 4];
                float w2c = c < 4 ? wv0[c] : wv1[c - 4];
                float isc = c < 4 ? iv0[c] : iv1[c - 4];
                float xv = wh1 + w2c;
                float lk = xv > 0.f ? xv : ALPHA * xv;
                float attv = ef > 0.f ? __expf(lk * ef) * isc : 0.f;
                afrag[c] = (bf16)attv;
                if (c < 4) av0[c] = attv; else av1[c - 4] = attv;
            }
            *(f32x4*)(att_out + erow + jg) = av0;
            *(f32x4*)(att_out + erow + jg + 4) = av1;
            #pragma unroll
            for (int ft = 0; ft < 4; ++ft) {
                bf16x8 bfrag = *(const bf16x8*)(WhT + (size_t)(ft * 16 + n16) * NN + jg);
                acc[ft] = __builtin_amdgcn_mfma_f32_16x16x32_bf16(afrag, bfrag, acc[ft], 0, 0, 0);
            }
        }
    }
    // C/D layout: col = lane&15, row = (lane>>4)*4 + reg
    #pragma unroll
    for (int ft = 0; ft < 4; ++ft) {
        #pragma unroll
        for (int r = 0; r < 4; ++r) {
            int row_l = quad * 4 + r;
            int i_g = itile * 64 + wave * 16 + row_l;
            size_t idx = (((size_t)jp * K_CH + kch) * NN + i_g) * OUT_F + ft * 16 + n16;
            hp_part[idx] = acc[ft][r];
        }
    }
}

// ---------------- k3: out[i][k*64+f] = elu(sum_jp hp_part)
__global__ __launch_bounds__(256) void k3_combine(const float* __restrict__ hp_part,
                                                  float* __restrict__ out) {
    int g = blockIdx.x * 256 + threadIdx.x;
    int i = g >> 8;
    int rem = g & 255;
    int kch = rem >> 6;
    int f = rem & 63;
    float s = 0.f;
    #pragma unroll
    for (int z = 0; z < 4; ++z)
        s += hp_part[(((size_t)z * K_CH + kch) * NN + i) * OUT_F + f];
    out[g] = s > 0.f ? s : __expf(s) - 1.f;
}

extern "C" void kernel_launch(void* const* d_in, const int* in_sizes, int n_in,
                              void* d_out, int out_size, void* d_ws, size_t ws_size,
                              hipStream_t stream) {
    (void)out_size; (void)ws_size;
    // identify inputs by element count (all four are distinct)
    const float *h = nullptr, *edge = nullptr, *W = nullptr, *a = nullptr;
    for (int i = 0; i < n_in; ++i) {
        int sz = in_sizes[i];
        if (sz == NN * IN_F)               h    = (const float*)d_in[i];
        else if (sz == K_CH * NN * NN)     edge = (const float*)d_in[i];
        else if (sz == IN_F * OUT_F)       W    = (const float*)d_in[i];
        else if (sz == 2 * OUT_F)          a    = (const float*)d_in[i];
    }

    char* ws = (char*)d_ws;
    float* Wh    = (float*)(ws);                        // 1 MB
    float* Wh1   = (float*)(ws + 1048576);              // 16 KB
    float* Wh2   = (float*)(ws + 1048576 + 16384);      // 16 KB
    float* s_col = (float*)(ws + 1048576 + 32768);      // 64 KB
    bf16*  WhT   = (bf16*) (ws + 1048576 + 32768 + 65536);            // 512 KB
    float* hp    = (float*)(ws + 1048576 + 32768 + 65536 + 524288);   // 16 MB

    float* out_h   = (float*)d_out;
    float* att_out = out_h + (size_t)NN * (K_CH * OUT_F);

    hipMemsetAsync(s_col, 0, K_CH * NN * sizeof(float), stream);
    k0_wh<<<dim3(NN / 4), 256, 0, stream>>>(h, W, a, Wh, Wh1, Wh2);
    k0_transpose<<<dim3(NN / 64), 256, 0, stream>>>(Wh, WhT);
    k1_colsum<<<dim3(64, 2, 4), 256, 0, stream>>>(edge, Wh1, Wh2, s_col);
    k2_fused<<<dim3(64, 4, 4), 256, 0, stream>>>(edge, Wh1, Wh2, s_col, WhT, att_out, hp);
    k3_combine<<<dim3((NN * K_CH * OUT_F) / 256), 256, 0, stream>>>(hp, out_h);
}